// Round 1
// baseline (233.992 us; speedup 1.0000x reference)
//
#include <hip/hip_runtime.h>

#define BB 32
#define SS 512
#define LL 64
#define TSTART 61
#define TSTOP 62

// One kernel, grid = 64 blocks x 256 threads.
// Blocks 0..31: forward recursion for batch b (single wave; lanes = states).
// Blocks 32..63: labeled path score for batch b-32 (256 threads, gather+reduce).
__global__ __launch_bounds__(256) void crf_kernel(
    const float* __restrict__ enc,   // [B][S][L] f32
    const float* __restrict__ Tr,    // [L][L]    f32
    const int*   __restrict__ lens,  // [B]
    const int*   __restrict__ tags,  // [B][S]
    float*       __restrict__ out)   // [2*B]: unlabeled | labeled
{
    if (blockIdx.x < BB) {
        // ---------------- forward (unlabeled) path ----------------
        const int tid = threadIdx.x;
        if (tid >= 64) return;            // single wave; no barriers below
        const int b = blockIdx.x;
        const int j = tid;                // this lane's state index
        const int len = lens[b];
        const float* eb = enc + b * (SS * LL);

        __shared__ __align__(16) float pbuf[2][LL];    // alpha (linear space), double-buffered
        __shared__ __align__(16) float ldsE[2][256];   // staged encoder scores, 4 steps/chunk

        // E column for this lane: E[i][j] = exp(T[i][j]) * 2^-7 (scale deferred to log)
        float Ecol[LL];
        #pragma unroll
        for (int i = 0; i < LL; ++i)
            Ecol[i] = __expf(Tr[i * LL + j]) * 0.0078125f;

        // alpha0[j] = T[START][j] + e[0][j]; normalize to linear space
        float alpha0 = Tr[TSTART * LL + j] + eb[j];
        float m = alpha0;
        #pragma unroll
        for (int off = 32; off; off >>= 1)
            m = fmaxf(m, __shfl_xor(m, off));
        float a = __expf(alpha0 - m);
        float logscale = m;
        pbuf[0][j] = a;
        int buf = 0;

        // encoder-score streaming pipeline: chunk c = e[4c..4c+3][:] = 256 floats
        const float4* ev = reinterpret_cast<const float4*>(eb);
        float4 vnext;
        {
            float4 v0 = ev[j];                                    // chunk 0
            *reinterpret_cast<float4*>(&ldsE[0][4 * j]) = v0;
            vnext = ev[64 + j];                                   // chunk 1 in flight
        }
        const int nchunk = (len + 3) >> 2;
        for (int c = 0; c < nchunk; ++c) {
            // stage chunk c+1 into LDS, issue load for chunk c+2 (~8-step lookahead)
            *reinterpret_cast<float4*>(&ldsE[(c + 1) & 1][4 * j]) = vnext;
            const int cpre = (c + 2 < 128) ? (c + 2) : 127;
            vnext = ev[cpre * 64 + j];
            const float* ecur = ldsE[c & 1];
            #pragma unroll
            for (int k = 0; k < 4; ++k) {
                const int t = 4 * c + k;
                if (t >= 1 && t < len) {               // wave-uniform
                    float w = __expf(ecur[k * 64 + j]);
                    const float4* p4 = reinterpret_cast<const float4*>(pbuf[buf]);
                    float s0 = 0.f, s1 = 0.f, s2 = 0.f, s3 = 0.f;
                    #pragma unroll
                    for (int q = 0; q < 16; ++q) {     // 16x b128 broadcast reads
                        float4 p = p4[q];
                        s0 = fmaf(p.x, Ecol[4 * q + 0], s0);
                        s1 = fmaf(p.y, Ecol[4 * q + 1], s1);
                        s2 = fmaf(p.z, Ecol[4 * q + 2], s2);
                        s3 = fmaf(p.w, Ecol[4 * q + 3], s3);
                    }
                    a = ((s0 + s1) + (s2 + s3)) * w;
                    if ((t & 7) == 7) {                // periodic rescale (amortized max)
                        float mm = a;
                        #pragma unroll
                        for (int off = 32; off; off >>= 1)
                            mm = fmaxf(mm, __shfl_xor(mm, off));
                        logscale += __logf(mm);
                        a = a / mm;
                    }
                    pbuf[buf ^ 1][j] = a;
                    buf ^= 1;
                }
            }
        }

        // unlabeled[b] = logscale + (len-1)*7*ln2 + log( sum_j a_j * exp(T[j][STOP]) )
        float f = a * __expf(Tr[j * LL + TSTOP]);
        float ssum = f;
        #pragma unroll
        for (int off = 32; off; off >>= 1)
            ssum += __shfl_xor(ssum, off);
        if (j == 0) {
            const float LN2x7 = 7.0f * 0.69314718055994530942f;
            out[b] = logscale + (float)(len - 1) * LN2x7 + __logf(ssum);
        }
    } else {
        // ---------------- labeled path ----------------
        const int b = blockIdx.x - BB;
        const int tid = threadIdx.x;
        const int len = lens[b];
        const int* tg = tags + b * SS;
        const float* eb = enc + b * (SS * LL);

        float acc = 0.f;
        for (int t = 1 + tid; t < len; t += 256) {
            int curt = tg[t], prevt = tg[t - 1];
            acc += Tr[prevt * LL + curt] + eb[t * LL + curt];
        }
        #pragma unroll
        for (int off = 32; off; off >>= 1)
            acc += __shfl_xor(acc, off);
        __shared__ float red[4];
        if ((tid & 63) == 0) red[tid >> 6] = acc;
        __syncthreads();
        if (tid == 0) {
            float tot = (red[0] + red[1]) + (red[2] + red[3]);
            int t0 = tg[0];
            int te = tg[len - 1];
            tot += Tr[TSTART * LL + t0] + eb[t0];   // begin
            tot += Tr[te * LL + TSTOP];             // end transition
            out[BB + b] = tot;
        }
    }
}

extern "C" void kernel_launch(void* const* d_in, const int* in_sizes, int n_in,
                              void* d_out, int out_size, void* d_ws, size_t ws_size,
                              hipStream_t stream) {
    const float* enc  = (const float*)d_in[0];
    const float* Tr   = (const float*)d_in[1];
    const int*   lens = (const int*)d_in[2];
    const int*   tags = (const int*)d_in[3];
    // d_in[4] (mask) unused: recomputed from lens
    float* out = (float*)d_out;
    crf_kernel<<<2 * BB, 256, 0, stream>>>(enc, Tr, lens, tags, out);
}

// Round 2
// 194.015 us; speedup vs baseline: 1.2061x; 1.2061x over previous
//
#include <hip/hip_runtime.h>

#define BB 32
#define SS 512
#define LL 64
#define TSTART 61
#define TSTOP 62

// Grid = 64 blocks x 256 threads.
// Blocks 0..31: forward recursion for batch b (single wave; lanes = states).
//   Alpha broadcast via v_readlane (register-only chain, no LDS round-trip).
// Blocks 32..63: labeled path score for batch b-32.
__global__ __launch_bounds__(256) void crf_kernel(
    const float* __restrict__ enc,   // [B][S][L] f32
    const float* __restrict__ Tr,    // [L][L]    f32
    const int*   __restrict__ lens,  // [B]
    const int*   __restrict__ tags,  // [B][S]
    float*       __restrict__ out)   // [2*B]: unlabeled | labeled
{
    if (blockIdx.x < BB) {
        // ---------------- forward (unlabeled) path ----------------
        const int tid = threadIdx.x;
        if (tid >= 64) return;            // single wave; no barriers
        const int b = blockIdx.x;
        const int j = tid;                // this lane's state index
        const int len = lens[b];
        const float* eb = enc + b * (SS * LL);

        // E column for this lane: E[i][j] = exp(T[i][j]) * 2^-7 (scale deferred)
        float Ecol[LL];
        #pragma unroll
        for (int i = 0; i < LL; ++i)
            Ecol[i] = __expf(Tr[i * LL + j]) * 0.0078125f;

        // alpha0[j] = T[START][j] + e[0][j]; move to linear space, normalized
        float alpha0 = Tr[TSTART * LL + j] + eb[j];
        float m = alpha0;
        #pragma unroll
        for (int off = 32; off; off >>= 1)
            m = fmaxf(m, __shfl_xor(m, off));
        float a = __expf(alpha0 - m);
        float logscale = m;

        // encoder-score register pipeline: chunk c = steps 4c..4c+3
        // lane j loads e[t][j] (coalesced across lanes), 2 chunks lookahead
        float ecur[4], enext[4];
        #pragma unroll
        for (int k = 0; k < 4; ++k) ecur[k] = eb[k * LL + j];          // chunk 0
        #pragma unroll
        for (int k = 0; k < 4; ++k) enext[k] = eb[(4 + k) * LL + j];   // chunk 1

        const int nchunk = (len + 3) >> 2;
        for (int c = 0; c < nchunk; ++c) {
            // prefetch chunk c+2 (independent of the chain)
            const int cpre = (c + 2 < 128) ? (c + 2) : 127;
            float efar[4];
            #pragma unroll
            for (int k = 0; k < 4; ++k) efar[k] = eb[(4 * cpre + k) * LL + j];

            #pragma unroll
            for (int k = 0; k < 4; ++k) {
                const int t = 4 * c + k;
                if (t >= 1 && t < len) {            // wave-uniform
                    const float w = __expf(ecur[k]);
                    const int ai = __float_as_int(a);
                    float s0 = 0.f, s1 = 0.f, s2 = 0.f, s3 = 0.f;
                    #pragma unroll
                    for (int q = 0; q < 16; ++q) {  // 64x readlane broadcast + fma
                        s0 = fmaf(__int_as_float(__builtin_amdgcn_readlane(ai, 4 * q + 0)), Ecol[4 * q + 0], s0);
                        s1 = fmaf(__int_as_float(__builtin_amdgcn_readlane(ai, 4 * q + 1)), Ecol[4 * q + 1], s1);
                        s2 = fmaf(__int_as_float(__builtin_amdgcn_readlane(ai, 4 * q + 2)), Ecol[4 * q + 2], s2);
                        s3 = fmaf(__int_as_float(__builtin_amdgcn_readlane(ai, 4 * q + 3)), Ecol[4 * q + 3], s3);
                    }
                    a = ((s0 + s1) + (s2 + s3)) * w;
                    if ((t & 7) == 7) {             // periodic rescale
                        float mm = a;
                        #pragma unroll
                        for (int off = 32; off; off >>= 1)
                            mm = fmaxf(mm, __shfl_xor(mm, off));
                        logscale += __logf(mm);
                        a = a * (1.0f / mm);
                    }
                }
            }
            #pragma unroll
            for (int k = 0; k < 4; ++k) { ecur[k] = enext[k]; enext[k] = efar[k]; }
        }

        // unlabeled[b] = logscale + (len-1)*7*ln2 + log( sum_j a_j*exp(T[j][STOP]) )
        float f = a * __expf(Tr[j * LL + TSTOP]);
        float ssum = f;
        #pragma unroll
        for (int off = 32; off; off >>= 1)
            ssum += __shfl_xor(ssum, off);
        if (j == 0) {
            const float LN2x7 = 7.0f * 0.69314718055994530942f;
            out[b] = logscale + (float)(len - 1) * LN2x7 + __logf(ssum);
        }
    } else {
        // ---------------- labeled path ----------------
        const int b = blockIdx.x - BB;
        const int tid = threadIdx.x;
        const int len = lens[b];
        const int* tg = tags + b * SS;
        const float* eb = enc + b * (SS * LL);

        float acc = 0.f;
        for (int t = 1 + tid; t < len; t += 256) {
            int curt = tg[t], prevt = tg[t - 1];
            acc += Tr[prevt * LL + curt] + eb[t * LL + curt];
        }
        #pragma unroll
        for (int off = 32; off; off >>= 1)
            acc += __shfl_xor(acc, off);
        __shared__ float red[4];
        if ((tid & 63) == 0) red[tid >> 6] = acc;
        __syncthreads();
        if (tid == 0) {
            float tot = (red[0] + red[1]) + (red[2] + red[3]);
            int t0 = tg[0];
            int te = tg[len - 1];
            tot += Tr[TSTART * LL + t0] + eb[t0];   // begin
            tot += Tr[te * LL + TSTOP];             // end transition
            out[BB + b] = tot;
        }
    }
}

extern "C" void kernel_launch(void* const* d_in, const int* in_sizes, int n_in,
                              void* d_out, int out_size, void* d_ws, size_t ws_size,
                              hipStream_t stream) {
    const float* enc  = (const float*)d_in[0];
    const float* Tr   = (const float*)d_in[1];
    const int*   lens = (const int*)d_in[2];
    const int*   tags = (const int*)d_in[3];
    float* out = (float*)d_out;
    crf_kernel<<<2 * BB, 256, 0, stream>>>(enc, Tr, lens, tags, out);
}

// Round 3
// 143.352 us; speedup vs baseline: 1.6323x; 1.3534x over previous
//
#include <hip/hip_runtime.h>

#define BB 32
#define SS 512
#define LL 64
#define TSTART 61
#define TSTOP 62
#define NSEG 16
#define SEGLEN 32
#define QSTRIDE 19   // LDS [row][col] leading-dim pad: bank = (19*row+col)%32 -> <=2-way

typedef short short8 __attribute__((ext_vector_type(8)));
typedef float floatx4 __attribute__((ext_vector_type(4)));

union S8 { int i[4]; short8 v; };

__device__ inline int pack_bf16(float a, float b) {   // low short = bf16(a) (truncation)
    unsigned ua = __float_as_uint(a), ub = __float_as_uint(b);
    return (int)((ua >> 16) | (ub & 0xffff0000u));
}

// ---------------- Kernel 1: segment transfer-matrix products ----------------
// Blocks 0..511: 4 waves/block; global unit u = blockIdx*4+waveid in [0,2048):
//   b = u>>6, s = (u>>2)&15 (segment of 32 steps), g = u&3 (16-col block).
//   Wave evolves Q[:, 16g..16g+16) (64x16, LDS f32 [row][col], stride 19) through
//   M_t = D(exp(e_t)) * E^T for t in [32s+1, 32s+33) intersect [1,len).
//   E^T (bf16, scaled 2^-7) is the fixed MFMA A operand in registers.
//   Output: ws Q^T stored [c_global][row] f32 + per-unit log-scale.
// Blocks 512..543: labeled path for batch blockIdx-512.
__global__ __launch_bounds__(256) void crf_seg_kernel(
    const float* __restrict__ enc, const float* __restrict__ Tr,
    const int* __restrict__ lens, const int* __restrict__ tags,
    float* __restrict__ wsQ, float* __restrict__ wsS,
    float* __restrict__ out)
{
    if (blockIdx.x >= 512) {
        // ---------------- labeled path ----------------
        const int b = blockIdx.x - 512;
        const int tid = threadIdx.x;
        const int len = lens[b];
        const int* tg = tags + b * SS;
        const float* eb = enc + b * (SS * LL);
        float acc = 0.f;
        for (int t = 1 + tid; t < len; t += 256) {
            int curt = tg[t], prevt = tg[t - 1];
            acc += Tr[prevt * LL + curt] + eb[t * LL + curt];
        }
        #pragma unroll
        for (int off = 32; off; off >>= 1) acc += __shfl_xor(acc, off);
        __shared__ float red[4];
        if ((tid & 63) == 0) red[tid >> 6] = acc;
        __syncthreads();
        if (tid == 0) {
            float tot = (red[0] + red[1]) + (red[2] + red[3]);
            int t0 = tg[0], te = tg[len - 1];
            tot += Tr[TSTART * LL + t0] + eb[t0];
            tot += Tr[te * LL + TSTOP];
            out[BB + b] = tot;
        }
        return;
    }

    const int wid  = threadIdx.x >> 6;
    const int lane = threadIdx.x & 63;
    const int unit = blockIdx.x * 4 + wid;
    const int b = unit >> 6;
    const int s = (unit >> 2) & 15;
    const int g = unit & 3;
    const int len = lens[b];
    const int q = lane >> 4;         // quad
    const int lcol = lane & 15;      // local column (n) / m within tile
    const float* eb = enc + b * (SS * LL);

    __shared__ __align__(16) float qbuf[4][LL * QSTRIDE];
    __shared__ __align__(16) float wbuf[4][LL];
    float* Q = qbuf[wid];
    float* W = wbuf[wid];

    // A operand: A[m][k] = E^T[m][k] = exp(T[k][m]) * 2^-7, bf16.
    // 16x16x32 A layout: m = 16*mt + (lane&15), k = 32*c2 + 8*q + idx.
    short8 Afr[4][2];
    #pragma unroll
    for (int mt = 0; mt < 4; ++mt)
        #pragma unroll
        for (int c2 = 0; c2 < 2; ++c2) {
            float av[8];
            #pragma unroll
            for (int idx = 0; idx < 8; ++idx) {
                int kk = 32 * c2 + 8 * q + idx;
                int mm = 16 * mt + lcol;
                av[idx] = __expf(Tr[kk * LL + mm]) * 0.0078125f;
            }
            S8 u;
            #pragma unroll
            for (int w2 = 0; w2 < 4; ++w2) u.i[w2] = pack_bf16(av[2 * w2], av[2 * w2 + 1]);
            Afr[mt][c2] = u.v;
        }

    // Q init = identity columns [16g, 16g+16)
    #pragma unroll
    for (int rr = 0; rr < 16; ++rr) {
        int row = 16 * q + rr;
        Q[row * QSTRIDE + lcol] = (row == 16 * g + lcol) ? 1.0f : 0.0f;
    }

    float lg = 0.0f;
    const int tlo = SEGLEN * s + 1;

    float ecur[8], enxt[8];
    #pragma unroll
    for (int k = 0; k < 8; ++k) ecur[k] = eb[min(tlo + k, SS - 1) * LL + lane];
    #pragma unroll
    for (int k = 0; k < 8; ++k) enxt[k] = eb[min(tlo + 8 + k, SS - 1) * LL + lane];

    for (int cc = 0; cc < 4; ++cc) {
        float epre[8];
        #pragma unroll
        for (int k = 0; k < 8; ++k) epre[k] = eb[min(tlo + 8 * (cc + 2) + k, SS - 1) * LL + lane];

        #pragma unroll
        for (int k = 0; k < 8; ++k) {
            const int t = tlo + 8 * cc + k;
            if (t < len) {                       // wave-uniform (len <= 512)
                W[lane] = __expf(ecur[k]);       // w_t[row], LDS, in-order wrt reads below
                // B operand: B[k][n] = Q[32*c2+8q+idx][lcol]
                float bv[16];
                #pragma unroll
                for (int c2 = 0; c2 < 2; ++c2)
                    #pragma unroll
                    for (int idx = 0; idx < 8; ++idx)
                        bv[c2 * 8 + idx] = Q[(32 * c2 + 8 * q + idx) * QSTRIDE + lcol];
                short8 Bfr[2];
                #pragma unroll
                for (int c2 = 0; c2 < 2; ++c2) {
                    S8 u;
                    #pragma unroll
                    for (int w2 = 0; w2 < 4; ++w2)
                        u.i[w2] = pack_bf16(bv[c2 * 8 + 2 * w2], bv[c2 * 8 + 2 * w2 + 1]);
                    Bfr[c2] = u.v;
                }
                floatx4 acc[4];
                #pragma unroll
                for (int mt = 0; mt < 4; ++mt) {
                    floatx4 z = {0.f, 0.f, 0.f, 0.f};
                    z = __builtin_amdgcn_mfma_f32_16x16x32_bf16(Afr[mt][0], Bfr[0], z, 0, 0, 0);
                    z = __builtin_amdgcn_mfma_f32_16x16x32_bf16(Afr[mt][1], Bfr[1], z, 0, 0, 0);
                    acc[mt] = z;
                }
                // apply w on output rows: row = 16mt + 4q + r
                float ov[4][4];
                #pragma unroll
                for (int mt = 0; mt < 4; ++mt) {
                    float4 wv = *(const float4*)(W + 16 * mt + 4 * q);
                    ov[mt][0] = acc[mt][0] * wv.x;
                    ov[mt][1] = acc[mt][1] * wv.y;
                    ov[mt][2] = acc[mt][2] * wv.z;
                    ov[mt][3] = acc[mt][3] * wv.w;
                }
                if (k == 7) {                    // periodic rescale (max -> 1)
                    float mx = ov[0][0];
                    #pragma unroll
                    for (int mt = 0; mt < 4; ++mt)
                        #pragma unroll
                        for (int r = 0; r < 4; ++r) mx = fmaxf(mx, ov[mt][r]);
                    #pragma unroll
                    for (int off = 32; off; off >>= 1) mx = fmaxf(mx, __shfl_xor(mx, off));
                    lg += __logf(mx);
                    float rmx = 1.0f / mx;
                    #pragma unroll
                    for (int mt = 0; mt < 4; ++mt)
                        #pragma unroll
                        for (int r = 0; r < 4; ++r) ov[mt][r] *= rmx;
                }
                #pragma unroll
                for (int mt = 0; mt < 4; ++mt)
                    #pragma unroll
                    for (int r = 0; r < 4; ++r)
                        Q[(16 * mt + 4 * q + r) * QSTRIDE + lcol] = ov[mt][r];
            }
        }
        #pragma unroll
        for (int k = 0; k < 8; ++k) { ecur[k] = enxt[k]; enxt[k] = epre[k]; }
    }

    // writeout: wsQ[(b*16+s)*4096 + c_global*64 + row], c_global = 16g + c_local
    float* qdst = wsQ + (size_t)(b * NSEG + s) * 4096 + (size_t)g * 16 * 64;
    const int cl = lane >> 2;          // local col 0..15
    const int rb = lane & 3;           // row block: rows 16*rb..+16
    #pragma unroll
    for (int wi = 0; wi < 4; ++wi) {
        float4 v;
        int r0 = rb * 16 + 4 * wi;
        v.x = Q[(r0 + 0) * QSTRIDE + cl];
        v.y = Q[(r0 + 1) * QSTRIDE + cl];
        v.z = Q[(r0 + 2) * QSTRIDE + cl];
        v.w = Q[(r0 + 3) * QSTRIDE + cl];
        *(float4*)(qdst + cl * 64 + r0) = v;
    }
    if (lane == 0) wsS[(b * NSEG + s) * 4 + g] = lg;
}

// ---------------- Kernel 2: fold a0 through the 16 segment products ----------------
__global__ __launch_bounds__(64) void crf_combine_kernel(
    const float* __restrict__ enc, const float* __restrict__ Tr,
    const int* __restrict__ lens,
    const float* __restrict__ wsQ, const float* __restrict__ wsS,
    float* __restrict__ out)
{
    const int b = blockIdx.x;
    const int j = threadIdx.x;       // lane = row/state
    const int len = lens[b];
    const float* qb = wsQ + (size_t)b * NSEG * 4096;

    float alpha0 = Tr[TSTART * LL + j] + enc[b * (SS * LL) + j];
    float m = alpha0;
    #pragma unroll
    for (int off = 32; off; off >>= 1) m = fmaxf(m, __shfl_xor(m, off));
    float a = __expf(alpha0 - m);
    float logscale = m;

    float myscale = wsS[b * (NSEG * 4) + j];   // (s,g) = (j>>2, j&3)

    float m0[64], m1[64], m2[64];
    #pragma unroll
    for (int c = 0; c < 64; ++c) m0[c] = qb[c * 64 + j];          // seg 0
    #pragma unroll
    for (int c = 0; c < 64; ++c) m1[c] = qb[4096 + c * 64 + j];   // seg 1

    auto step = [&](int s, float (&cur)[64], float (&pre)[64]) {
        const float* qn = qb + (size_t)min(s + 2, NSEG - 1) * 4096;
        #pragma unroll
        for (int c = 0; c < 64; ++c) pre[c] = qn[c * 64 + j];
        float l0 = __shfl(myscale, 4 * s + 0);
        float l1 = __shfl(myscale, 4 * s + 1);
        float l2 = __shfl(myscale, 4 * s + 2);
        float l3 = __shfl(myscale, 4 * s + 3);
        float lmax = fmaxf(fmaxf(l0, l1), fmaxf(l2, l3));
        int grp = j >> 4;
        float lgg = (grp == 0) ? l0 : (grp == 1) ? l1 : (grp == 2) ? l2 : l3;
        float at = a * __expf(lgg - lmax);
        int ai = __float_as_int(at);
        float s0 = 0.f, s1 = 0.f, s2 = 0.f, s3 = 0.f;
        #pragma unroll
        for (int c = 0; c < 16; ++c) {
            s0 = fmaf(__int_as_float(__builtin_amdgcn_readlane(ai, 4 * c + 0)), cur[4 * c + 0], s0);
            s1 = fmaf(__int_as_float(__builtin_amdgcn_readlane(ai, 4 * c + 1)), cur[4 * c + 1], s1);
            s2 = fmaf(__int_as_float(__builtin_amdgcn_readlane(ai, 4 * c + 2)), cur[4 * c + 2], s2);
            s3 = fmaf(__int_as_float(__builtin_amdgcn_readlane(ai, 4 * c + 3)), cur[4 * c + 3], s3);
        }
        float an = ((s0 + s1) + (s2 + s3));
        float mx = an;
        #pragma unroll
        for (int off = 32; off; off >>= 1) mx = fmaxf(mx, __shfl_xor(mx, off));
        a = an * (1.0f / mx);
        logscale += lmax + __logf(mx);
    };

    for (int s = 0; s < 15; s += 3) {
        step(s,     m0, m2);
        step(s + 1, m1, m0);
        step(s + 2, m2, m1);
    }
    step(15, m0, m2);   // seg 15 (prefetch clamps, redundant)

    float f = a * __expf(Tr[j * LL + TSTOP]);
    float ssum = f;
    #pragma unroll
    for (int off = 32; off; off >>= 1) ssum += __shfl_xor(ssum, off);
    if (j == 0) {
        const float LN2x7 = 7.0f * 0.69314718055994530942f;
        out[b] = logscale + (float)(len - 1) * LN2x7 + __logf(ssum);
    }
}

// ---------------- Fallback (R2 kernel, used if ws too small) ----------------
__global__ __launch_bounds__(256) void crf_kernel_fb(
    const float* __restrict__ enc, const float* __restrict__ Tr,
    const int* __restrict__ lens, const int* __restrict__ tags,
    float* __restrict__ out)
{
    if (blockIdx.x < BB) {
        const int tid = threadIdx.x;
        if (tid >= 64) return;
        const int b = blockIdx.x;
        const int j = tid;
        const int len = lens[b];
        const float* eb = enc + b * (SS * LL);
        float Ecol[LL];
        #pragma unroll
        for (int i = 0; i < LL; ++i) Ecol[i] = __expf(Tr[i * LL + j]) * 0.0078125f;
        float alpha0 = Tr[TSTART * LL + j] + eb[j];
        float m = alpha0;
        #pragma unroll
        for (int off = 32; off; off >>= 1) m = fmaxf(m, __shfl_xor(m, off));
        float a = __expf(alpha0 - m);
        float logscale = m;
        float ecur[4], enext[4];
        #pragma unroll
        for (int k = 0; k < 4; ++k) ecur[k] = eb[k * LL + j];
        #pragma unroll
        for (int k = 0; k < 4; ++k) enext[k] = eb[(4 + k) * LL + j];
        const int nchunk = (len + 3) >> 2;
        for (int c = 0; c < nchunk; ++c) {
            const int cpre = (c + 2 < 128) ? (c + 2) : 127;
            float efar[4];
            #pragma unroll
            for (int k = 0; k < 4; ++k) efar[k] = eb[(4 * cpre + k) * LL + j];
            #pragma unroll
            for (int k = 0; k < 4; ++k) {
                const int t = 4 * c + k;
                if (t >= 1 && t < len) {
                    const float w = __expf(ecur[k]);
                    const int ai = __float_as_int(a);
                    float s0 = 0.f, s1 = 0.f, s2 = 0.f, s3 = 0.f;
                    #pragma unroll
                    for (int qq = 0; qq < 16; ++qq) {
                        s0 = fmaf(__int_as_float(__builtin_amdgcn_readlane(ai, 4 * qq + 0)), Ecol[4 * qq + 0], s0);
                        s1 = fmaf(__int_as_float(__builtin_amdgcn_readlane(ai, 4 * qq + 1)), Ecol[4 * qq + 1], s1);
                        s2 = fmaf(__int_as_float(__builtin_amdgcn_readlane(ai, 4 * qq + 2)), Ecol[4 * qq + 2], s2);
                        s3 = fmaf(__int_as_float(__builtin_amdgcn_readlane(ai, 4 * qq + 3)), Ecol[4 * qq + 3], s3);
                    }
                    a = ((s0 + s1) + (s2 + s3)) * w;
                    if ((t & 7) == 7) {
                        float mm = a;
                        #pragma unroll
                        for (int off = 32; off; off >>= 1) mm = fmaxf(mm, __shfl_xor(mm, off));
                        logscale += __logf(mm);
                        a = a * (1.0f / mm);
                    }
                }
            }
            #pragma unroll
            for (int k = 0; k < 4; ++k) { ecur[k] = enext[k]; enext[k] = efar[k]; }
        }
        float f = a * __expf(Tr[j * LL + TSTOP]);
        float ssum = f;
        #pragma unroll
        for (int off = 32; off; off >>= 1) ssum += __shfl_xor(ssum, off);
        if (j == 0) {
            const float LN2x7 = 7.0f * 0.69314718055994530942f;
            out[b] = logscale + (float)(len - 1) * LN2x7 + __logf(ssum);
        }
    } else {
        const int b = blockIdx.x - BB;
        const int tid = threadIdx.x;
        const int len = lens[b];
        const int* tg = tags + b * SS;
        const float* eb = enc + b * (SS * LL);
        float acc = 0.f;
        for (int t = 1 + tid; t < len; t += 256) {
            int curt = tg[t], prevt = tg[t - 1];
            acc += Tr[prevt * LL + curt] + eb[t * LL + curt];
        }
        #pragma unroll
        for (int off = 32; off; off >>= 1) acc += __shfl_xor(acc, off);
        __shared__ float red[4];
        if ((tid & 63) == 0) red[tid >> 6] = acc;
        __syncthreads();
        if (tid == 0) {
            float tot = (red[0] + red[1]) + (red[2] + red[3]);
            int t0 = tg[0], te = tg[len - 1];
            tot += Tr[TSTART * LL + t0] + eb[t0];
            tot += Tr[te * LL + TSTOP];
            out[BB + b] = tot;
        }
    }
}

extern "C" void kernel_launch(void* const* d_in, const int* in_sizes, int n_in,
                              void* d_out, int out_size, void* d_ws, size_t ws_size,
                              hipStream_t stream) {
    const float* enc  = (const float*)d_in[0];
    const float* Tr   = (const float*)d_in[1];
    const int*   lens = (const int*)d_in[2];
    const int*   tags = (const int*)d_in[3];
    float* out = (float*)d_out;

    const size_t needQ = (size_t)BB * NSEG * 4096 * sizeof(float);   // 8 MB
    const size_t needS = (size_t)BB * NSEG * 4 * sizeof(float);      // 8 KB
    if (ws_size >= needQ + needS) {
        float* wsQ = (float*)d_ws;
        float* wsS = (float*)((char*)d_ws + needQ);
        crf_seg_kernel<<<544, 256, 0, stream>>>(enc, Tr, lens, tags, wsQ, wsS, out);
        crf_combine_kernel<<<BB, 64, 0, stream>>>(enc, Tr, lens, wsQ, wsS, out);
    } else {
        crf_kernel_fb<<<2 * BB, 256, 0, stream>>>(enc, Tr, lens, tags, out);
    }
}

// Round 4
// 98.549 us; speedup vs baseline: 2.3744x; 1.4546x over previous
//
#include <hip/hip_runtime.h>

#define BB 32
#define SS 512
#define LL 64
#define TSTART 61
#define TSTOP 62
#define NSEG 16
#define SEGLEN 32
#define QPAD 68   // QT row stride (floats); bank spread ~= stride-1 baseline

typedef short short8 __attribute__((ext_vector_type(8)));
typedef float floatx4 __attribute__((ext_vector_type(4)));

union S8 { int i[4]; short8 v; };

__device__ inline unsigned bf16_rne(float x) {        // round-to-nearest-even
    unsigned u = __float_as_uint(x);
    u += 0x7fffu + ((u >> 16) & 1u);
    return u >> 16;
}
__device__ inline int pack_bf16(float a, float b) {
    return (int)(bf16_rne(a) | (bf16_rne(b) << 16));
}

// ---------------- Kernel 1: segment transfer-matrix products ----------------
// Blocks 0..2047: one wave each; unit = blockIdx: b=unit>>6, s=(unit>>2)&15, g=unit&3.
//   Computes P_seg = D(w_last) * prod[E^T D(w_t)] * E^T for cols [16g,16g+16),
//   A=E^T constant in regs, running product transposed in LDS (QT[col][row]),
//   w pre-staged per 8-step chunk (no in-step LDS dependency on w).
// Blocks 2048..2079: labeled path for batch blockIdx-2048 (single wave).
__global__ __launch_bounds__(64) void crf_seg_kernel(
    const float* __restrict__ enc, const float* __restrict__ Tr,
    const int* __restrict__ lens, const int* __restrict__ tags,
    float* __restrict__ wsQ, float* __restrict__ wsS,
    float* __restrict__ out)
{
    const int blk = blockIdx.x;
    if (blk >= BB * NSEG * 4) {
        // ---------------- labeled path (one wave) ----------------
        const int b = blk - BB * NSEG * 4;
        const int tid = threadIdx.x;
        const int len = lens[b];
        const int* tg = tags + b * SS;
        const float* eb = enc + b * (SS * LL);
        float acc = 0.f;
        for (int t = 1 + tid; t < len; t += 64) {
            int curt = tg[t], prevt = tg[t - 1];
            acc += Tr[prevt * LL + curt] + eb[t * LL + curt];
        }
        #pragma unroll
        for (int off = 32; off; off >>= 1) acc += __shfl_xor(acc, off);
        if (tid == 0) {
            int t0 = tg[0], te = tg[len - 1];
            acc += Tr[TSTART * LL + t0] + eb[t0];
            acc += Tr[te * LL + TSTOP];
            out[BB + b] = acc;
        }
        return;
    }

    const int lane = threadIdx.x;
    const int b = blk >> 6;
    const int s = (blk >> 2) & 15;
    const int g = blk & 3;
    const int len = lens[b];
    const int q = lane >> 4;
    const int lcol = lane & 15;
    const float* eb = enc + b * (SS * LL);
    const int tlo = SEGLEN * s + 1;
    const int Teff = min(max(len - tlo, 0), SEGLEN);

    float* qdst = wsQ + (size_t)(b * NSEG + s) * 4096;

    if (Teff <= 0) {   // segment entirely past len: transfer = identity
        #pragma unroll
        for (int u = 0; u < 4; ++u) {
            int r0 = 16 * q + 4 * u;
            float4 v;
            v.x = (r0 + 0 == 16 * g + lcol) ? 1.f : 0.f;
            v.y = (r0 + 1 == 16 * g + lcol) ? 1.f : 0.f;
            v.z = (r0 + 2 == 16 * g + lcol) ? 1.f : 0.f;
            v.w = (r0 + 3 == 16 * g + lcol) ? 1.f : 0.f;
            *(float4*)(qdst + (16 * g + lcol) * 64 + r0) = v;
        }
        if (lane == 0) wsS[(b * NSEG + s) * 4 + g] = 0.f;
        return;
    }

    __shared__ __align__(16) float QT[16 * QPAD];   // running product, [col][row]
    __shared__ __align__(16) float W32[32 * 64];    // staged w vectors, [tt][row]

    // A operand: A[m][k] = E^T[m][k] = exp(T[k][m]) * 2^-7 (bf16, RNE)
    short8 Afr[4][2];
    #pragma unroll
    for (int mt = 0; mt < 4; ++mt)
        #pragma unroll
        for (int c2 = 0; c2 < 2; ++c2) {
            float av[8];
            #pragma unroll
            for (int idx = 0; idx < 8; ++idx) {
                int kk = 32 * c2 + 8 * q + idx;
                int mm = 16 * mt + lcol;
                av[idx] = __expf(Tr[kk * LL + mm]) * 0.0078125f;
            }
            S8 u;
            #pragma unroll
            for (int w2 = 0; w2 < 4; ++w2) u.i[w2] = pack_bf16(av[2 * w2], av[2 * w2 + 1]);
            Afr[mt][c2] = u.v;
        }

    // QT init: M = E^T[:, 16g+lcol]; lane covers rows 16q..16q+15 of its col
    {
        const float* trow = Tr + (16 * g + lcol) * LL;
        #pragma unroll
        for (int u = 0; u < 4; ++u) {
            float4 tv = *(const float4*)(trow + 16 * q + 4 * u);
            float4 ev;
            ev.x = __expf(tv.x) * 0.0078125f;
            ev.y = __expf(tv.y) * 0.0078125f;
            ev.z = __expf(tv.z) * 0.0078125f;
            ev.w = __expf(tv.w) * 0.0078125f;
            *(float4*)(QT + lcol * QPAD + 16 * q + 4 * u) = ev;
        }
    }

    float lg = 0.0f;
    float ecur[8], enxt[8];
    #pragma unroll
    for (int k = 0; k < 8; ++k) ecur[k] = eb[min(tlo + k, SS - 1) * LL + lane];
    #pragma unroll
    for (int k = 0; k < 8; ++k) enxt[k] = eb[min(tlo + 8 + k, SS - 1) * LL + lane];

    for (int cc = 0; cc < 4; ++cc) {
        // stage this chunk's w vectors (rows tt = 8cc..8cc+7) — off critical path
        #pragma unroll
        for (int k = 0; k < 8; ++k) W32[(8 * cc + k) * 64 + lane] = __expf(ecur[k]);
        // prefetch enc chunk cc+2
        float epre[8];
        #pragma unroll
        for (int k = 0; k < 8; ++k) epre[k] = eb[min(tlo + 8 * (cc + 2) + k, SS - 1) * LL + lane];

        #pragma unroll
        for (int k = 0; k < 8; ++k) {
            const int i = 8 * cc + k + 2;     // MFMA step index, 2..33
            if (i <= Teff) {                  // wave-uniform
                const int wloc = 8 * cc + k;  // uses w_{tlo+i-2}
                float4 qv[2][2], wv[2][2];
                #pragma unroll
                for (int c2 = 0; c2 < 2; ++c2)
                    #pragma unroll
                    for (int h = 0; h < 2; ++h) {
                        qv[c2][h] = *(const float4*)(QT + lcol * QPAD + 32 * c2 + 8 * q + 4 * h);
                        wv[c2][h] = *(const float4*)(W32 + wloc * 64 + 32 * c2 + 8 * q + 4 * h);
                    }
                short8 Bfr[2];
                #pragma unroll
                for (int c2 = 0; c2 < 2; ++c2) {
                    float bv[8];
                    bv[0] = qv[c2][0].x * wv[c2][0].x;  bv[1] = qv[c2][0].y * wv[c2][0].y;
                    bv[2] = qv[c2][0].z * wv[c2][0].z;  bv[3] = qv[c2][0].w * wv[c2][0].w;
                    bv[4] = qv[c2][1].x * wv[c2][1].x;  bv[5] = qv[c2][1].y * wv[c2][1].y;
                    bv[6] = qv[c2][1].z * wv[c2][1].z;  bv[7] = qv[c2][1].w * wv[c2][1].w;
                    S8 u;
                    #pragma unroll
                    for (int w2 = 0; w2 < 4; ++w2)
                        u.i[w2] = pack_bf16(bv[2 * w2], bv[2 * w2 + 1]);
                    Bfr[c2] = u.v;
                }
                float ov[4][4];
                #pragma unroll
                for (int mt = 0; mt < 4; ++mt) {
                    floatx4 z = {0.f, 0.f, 0.f, 0.f};
                    z = __builtin_amdgcn_mfma_f32_16x16x32_bf16(Afr[mt][0], Bfr[0], z, 0, 0, 0);
                    z = __builtin_amdgcn_mfma_f32_16x16x32_bf16(Afr[mt][1], Bfr[1], z, 0, 0, 0);
                    ov[mt][0] = z[0]; ov[mt][1] = z[1]; ov[mt][2] = z[2]; ov[mt][3] = z[3];
                }
                if (k == 7) {                 // periodic rescale
                    float mx = ov[0][0];
                    #pragma unroll
                    for (int mt = 0; mt < 4; ++mt)
                        #pragma unroll
                        for (int r = 0; r < 4; ++r) mx = fmaxf(mx, ov[mt][r]);
                    #pragma unroll
                    for (int off = 32; off; off >>= 1) mx = fmaxf(mx, __shfl_xor(mx, off));
                    lg += __logf(mx);
                    float rmx = 1.0f / mx;
                    #pragma unroll
                    for (int mt = 0; mt < 4; ++mt)
                        #pragma unroll
                        for (int r = 0; r < 4; ++r) ov[mt][r] *= rmx;
                }
                #pragma unroll
                for (int mt = 0; mt < 4; ++mt) {
                    float4 sv = make_float4(ov[mt][0], ov[mt][1], ov[mt][2], ov[mt][3]);
                    *(float4*)(QT + lcol * QPAD + 16 * mt + 4 * q) = sv;
                }
            }
        }
        #pragma unroll
        for (int k = 0; k < 8; ++k) { ecur[k] = enxt[k]; enxt[k] = epre[k]; }
    }

    // final row scale by w_{tlo+Teff-1}, write P^T [col][row] to ws
    const float* wl = W32 + (Teff - 1) * 64;
    #pragma unroll
    for (int u = 0; u < 4; ++u) {
        int r0 = 16 * q + 4 * u;
        float4 mv = *(const float4*)(QT + lcol * QPAD + r0);
        float4 wv = *(const float4*)(wl + r0);
        float4 o = make_float4(mv.x * wv.x, mv.y * wv.y, mv.z * wv.z, mv.w * wv.w);
        *(float4*)(qdst + (16 * g + lcol) * 64 + r0) = o;
    }
    if (lane == 0) wsS[(b * NSEG + s) * 4 + g] = lg;
}

// ---------------- Kernel 2: fold a0 through the 16 segment products ----------------
// One wave per batch. Two register banks (128 VGPR), 1-segment-ahead prefetch,
// role-swapped per parity — no third bank, no spills.
__global__ __launch_bounds__(64) void crf_combine_kernel(
    const float* __restrict__ enc, const float* __restrict__ Tr,
    const int* __restrict__ lens,
    const float* __restrict__ wsQ, const float* __restrict__ wsS,
    float* __restrict__ out)
{
    const int b = blockIdx.x;
    const int j = threadIdx.x;
    const int len = lens[b];
    const float* qb = wsQ + (size_t)b * NSEG * 4096;

    float alpha0 = Tr[TSTART * LL + j] + enc[b * (SS * LL) + j];
    float m = alpha0;
    #pragma unroll
    for (int off = 32; off; off >>= 1) m = fmaxf(m, __shfl_xor(m, off));
    float a = __expf(alpha0 - m);
    float logscale = m;

    float myscale = wsS[b * (NSEG * 4) + j];   // (s,g) = (j>>2, j&3)

    float A[64], Bv[64];
    #pragma unroll
    for (int c = 0; c < 64; ++c) A[c] = qb[c * 64 + j];   // seg 0

    auto step = [&](int s, float (&cur)[64]) {
        float l0 = __shfl(myscale, 4 * s + 0);
        float l1 = __shfl(myscale, 4 * s + 1);
        float l2 = __shfl(myscale, 4 * s + 2);
        float l3 = __shfl(myscale, 4 * s + 3);
        float lmax = fmaxf(fmaxf(l0, l1), fmaxf(l2, l3));
        int grp = j >> 4;
        float lgg = (grp == 0) ? l0 : (grp == 1) ? l1 : (grp == 2) ? l2 : l3;
        float at = a * __expf(lgg - lmax);
        int ai = __float_as_int(at);
        float s0 = 0.f, s1 = 0.f, s2 = 0.f, s3 = 0.f;
        #pragma unroll
        for (int c = 0; c < 16; ++c) {
            s0 = fmaf(__int_as_float(__builtin_amdgcn_readlane(ai, 4 * c + 0)), cur[4 * c + 0], s0);
            s1 = fmaf(__int_as_float(__builtin_amdgcn_readlane(ai, 4 * c + 1)), cur[4 * c + 1], s1);
            s2 = fmaf(__int_as_float(__builtin_amdgcn_readlane(ai, 4 * c + 2)), cur[4 * c + 2], s2);
            s3 = fmaf(__int_as_float(__builtin_amdgcn_readlane(ai, 4 * c + 3)), cur[4 * c + 3], s3);
        }
        float an = ((s0 + s1) + (s2 + s3));
        float mx = an;
        #pragma unroll
        for (int off = 32; off; off >>= 1) mx = fmaxf(mx, __shfl_xor(mx, off));
        a = an * (1.0f / mx);
        logscale += lmax + __logf(mx);
    };

    for (int s = 0; s < 16; s += 2) {
        const float* q1 = qb + (size_t)min(s + 1, NSEG - 1) * 4096;
        #pragma unroll
        for (int c = 0; c < 64; ++c) Bv[c] = q1[c * 64 + j];
        step(s, A);
        const float* q2 = qb + (size_t)min(s + 2, NSEG - 1) * 4096;
        #pragma unroll
        for (int c = 0; c < 64; ++c) A[c] = q2[c * 64 + j];
        step(s + 1, Bv);
    }

    float f = a * __expf(Tr[j * LL + TSTOP]);
    float ssum = f;
    #pragma unroll
    for (int off = 32; off; off >>= 1) ssum += __shfl_xor(ssum, off);
    if (j == 0) {
        const float LN2x7 = 7.0f * 0.69314718055994530942f;
        out[b] = logscale + (float)(len - 1) * LN2x7 + __logf(ssum);
    }
}

// ---------------- Fallback (exact, used if ws too small) ----------------
__global__ __launch_bounds__(256) void crf_kernel_fb(
    const float* __restrict__ enc, const float* __restrict__ Tr,
    const int* __restrict__ lens, const int* __restrict__ tags,
    float* __restrict__ out)
{
    if (blockIdx.x < BB) {
        const int tid = threadIdx.x;
        if (tid >= 64) return;
        const int b = blockIdx.x;
        const int j = tid;
        const int len = lens[b];
        const float* eb = enc + b * (SS * LL);
        float Ecol[LL];
        #pragma unroll
        for (int i = 0; i < LL; ++i) Ecol[i] = __expf(Tr[i * LL + j]) * 0.0078125f;
        float alpha0 = Tr[TSTART * LL + j] + eb[j];
        float m = alpha0;
        #pragma unroll
        for (int off = 32; off; off >>= 1) m = fmaxf(m, __shfl_xor(m, off));
        float a = __expf(alpha0 - m);
        float logscale = m;
        float ecur[4], enext[4];
        #pragma unroll
        for (int k = 0; k < 4; ++k) ecur[k] = eb[k * LL + j];
        #pragma unroll
        for (int k = 0; k < 4; ++k) enext[k] = eb[(4 + k) * LL + j];
        const int nchunk = (len + 3) >> 2;
        for (int c = 0; c < nchunk; ++c) {
            const int cpre = (c + 2 < 128) ? (c + 2) : 127;
            float efar[4];
            #pragma unroll
            for (int k = 0; k < 4; ++k) efar[k] = eb[(4 * cpre + k) * LL + j];
            #pragma unroll
            for (int k = 0; k < 4; ++k) {
                const int t = 4 * c + k;
                if (t >= 1 && t < len) {
                    const float w = __expf(ecur[k]);
                    const int ai = __float_as_int(a);
                    float s0 = 0.f, s1 = 0.f, s2 = 0.f, s3 = 0.f;
                    #pragma unroll
                    for (int qq = 0; qq < 16; ++qq) {
                        s0 = fmaf(__int_as_float(__builtin_amdgcn_readlane(ai, 4 * qq + 0)), Ecol[4 * qq + 0], s0);
                        s1 = fmaf(__int_as_float(__builtin_amdgcn_readlane(ai, 4 * qq + 1)), Ecol[4 * qq + 1], s1);
                        s2 = fmaf(__int_as_float(__builtin_amdgcn_readlane(ai, 4 * qq + 2)), Ecol[4 * qq + 2], s2);
                        s3 = fmaf(__int_as_float(__builtin_amdgcn_readlane(ai, 4 * qq + 3)), Ecol[4 * qq + 3], s3);
                    }
                    a = ((s0 + s1) + (s2 + s3)) * w;
                    if ((t & 7) == 7) {
                        float mm = a;
                        #pragma unroll
                        for (int off = 32; off; off >>= 1) mm = fmaxf(mm, __shfl_xor(mm, off));
                        logscale += __logf(mm);
                        a = a * (1.0f / mm);
                    }
                }
            }
            #pragma unroll
            for (int k = 0; k < 4; ++k) { ecur[k] = enext[k]; enext[k] = efar[k]; }
        }
        float f = a * __expf(Tr[j * LL + TSTOP]);
        float ssum = f;
        #pragma unroll
        for (int off = 32; off; off >>= 1) ssum += __shfl_xor(ssum, off);
        if (j == 0) {
            const float LN2x7 = 7.0f * 0.69314718055994530942f;
            out[b] = logscale + (float)(len - 1) * LN2x7 + __logf(ssum);
        }
    } else {
        const int b = blockIdx.x - BB;
        const int tid = threadIdx.x;
        const int len = lens[b];
        const int* tg = tags + b * SS;
        const float* eb = enc + b * (SS * LL);
        float acc = 0.f;
        for (int t = 1 + tid; t < len; t += 256) {
            int curt = tg[t], prevt = tg[t - 1];
            acc += Tr[prevt * LL + curt] + eb[t * LL + curt];
        }
        #pragma unroll
        for (int off = 32; off; off >>= 1) acc += __shfl_xor(acc, off);
        __shared__ float red[4];
        if ((tid & 63) == 0) red[tid >> 6] = acc;
        __syncthreads();
        if (tid == 0) {
            float tot = (red[0] + red[1]) + (red[2] + red[3]);
            int t0 = tg[0], te = tg[len - 1];
            tot += Tr[TSTART * LL + t0] + eb[t0];
            tot += Tr[te * LL + TSTOP];
            out[BB + b] = tot;
        }
    }
}

extern "C" void kernel_launch(void* const* d_in, const int* in_sizes, int n_in,
                              void* d_out, int out_size, void* d_ws, size_t ws_size,
                              hipStream_t stream) {
    const float* enc  = (const float*)d_in[0];
    const float* Tr   = (const float*)d_in[1];
    const int*   lens = (const int*)d_in[2];
    const int*   tags = (const int*)d_in[3];
    float* out = (float*)d_out;

    const size_t needQ = (size_t)BB * NSEG * 4096 * sizeof(float);   // 8 MB
    const size_t needS = (size_t)BB * NSEG * 4 * sizeof(float);      // 8 KB
    if (ws_size >= needQ + needS) {
        float* wsQ = (float*)d_ws;
        float* wsS = (float*)((char*)d_ws + needQ);
        crf_seg_kernel<<<BB * NSEG * 4 + BB, 64, 0, stream>>>(enc, Tr, lens, tags, wsQ, wsS, out);
        crf_combine_kernel<<<BB, 64, 0, stream>>>(enc, Tr, lens, wsQ, wsS, out);
    } else {
        crf_kernel_fb<<<2 * BB, 256, 0, stream>>>(enc, Tr, lens, tags, out);
    }
}